// Round 9
// baseline (274.301 us; speedup 1.0000x reference)
//
#include <hip/hip_runtime.h>
#include <math.h>

#define BB 4
#define EPSV 1e-5f

typedef __attribute__((ext_vector_type(8))) short short8;
typedef __attribute__((ext_vector_type(4))) float floatx4;
typedef __attribute__((ext_vector_type(4))) int intx4;
typedef __attribute__((ext_vector_type(4))) unsigned short ushort4v;

__device__ inline float b2f(unsigned short u) {
    unsigned v = ((unsigned)u) << 16;
    return __builtin_bit_cast(float, v);
}
__device__ inline unsigned short f2b(float f) {   // RNE
    unsigned u = __builtin_bit_cast(unsigned, f);
    u += 0x7FFFu + ((u >> 16) & 1u);
    return (unsigned short)(u >> 16);
}
__device__ inline unsigned short f2b_fast(float f) {  // round-half-up, 2 inst
    unsigned u = __builtin_bit_cast(unsigned, f);
    return (unsigned short)((u + 0x8000u) >> 16);
}

// ---------------------------------------------------------------------------
// Fused prep kernel: transpose + all 5 weight repacks in ONE launch.
// blockIdx.x ranges:
//   [0,1024)     : transpose x (fp32 NCHW) -> xb (bf16 NHWC)
//   [1024,1600)  : repack rb_w1 -> wf1   (conv frag, MPAD=128)
//   [1600,2176)  : repack rb_w2 -> wf2
//   [2176,2464)  : repack off_w -> wfO   (conv frag, MPAD=64, OCH=54)
//   [2464,3040)  : repack dc_w  -> wfD
//   [3040,3104)  : repack cv2_w -> wfC
// Weight frag order: dst[((step*NMT2+mt)*64+lane)*8+j] = W[oc][k],
//   oc = mt*16+(lane&15), k = step*32+(lane>>4)*8+j.
// conv3x3 K-order (4-phase): step = phase*9+tap, c = phase*32+(k&31)
// ---------------------------------------------------------------------------
__global__ __launch_bounds__(256) void prep_k(
    const float* __restrict__ x, unsigned short* __restrict__ xb,
    const float* __restrict__ rb_w1, unsigned short* __restrict__ wf1,
    const float* __restrict__ rb_w2, unsigned short* __restrict__ wf2,
    const float* __restrict__ off_w, unsigned short* __restrict__ wfO,
    const float* __restrict__ dc_w, unsigned short* __restrict__ wfD,
    const float* __restrict__ cv2_w, unsigned short* __restrict__ wfC)
{
    __shared__ unsigned short t[64][136];
    const int bid = blockIdx.x;
    const int tid = threadIdx.x;

    if (bid < 1024) {                       // ---- transpose ----
        const int px0 = (bid & 255) * 64;
        const int b = bid >> 8;
        const int pxr = tid & 63;
        const int c0 = tid >> 6;
#pragma unroll
        for (int i = 0; i < 32; ++i) {
            int c = c0 + i * 4;
            float v = x[(((size_t)b * 128 + c) << 14) + px0 + pxr];
            t[pxr][c] = f2b(v);
        }
        __syncthreads();
#pragma unroll
        for (int i = 0; i < 4; ++i) {
            int idx = tid + i * 256;
            int px = idx >> 4;
            int c8 = idx & 15;
            short8 v = *(const short8*)&t[px][c8 * 8];
            *(short8*)&xb[(((size_t)b << 14) + px0 + px) * 128 + c8 * 8] = v;
        }
        return;
    }
    if (bid < 2464) {                       // ---- conv-frag repacks (4-phase K-order) ----
        const float* w; unsigned short* dst; int MPAD, OCH, t0;
        if (bid < 1600)      { w = rb_w1; dst = wf1; MPAD = 128; OCH = 128; t0 = 1024; }
        else if (bid < 2176) { w = rb_w2; dst = wf2; MPAD = 128; OCH = 128; t0 = 1600; }
        else                 { w = off_w; dst = wfO; MPAD = 64;  OCH = 54;  t0 = 2176; }
        int tt = (bid - t0) * 256 + tid;
        if (tt >= 1152 * MPAD) return;
        const int NMT2 = MPAD / 16;
        int j = tt & 7, lane = (tt >> 3) & 63, rest = tt >> 9;
        int mt = rest % NMT2, step = rest / NMT2;
        int oc = mt * 16 + (lane & 15);
        int k = step * 32 + ((lane >> 4) << 3) + j;
        int phase = step / 9, tap = step % 9;
        int c = phase * 32 + (k & 31);
        float v = (oc < OCH) ? w[((size_t)oc * 128 + c) * 9 + tap] : 0.f;
        dst[tt] = f2b(v);
        return;
    }
    if (bid < 3040) {                       // ---- dc repack: k = dk*64+c ----
        int tt = (bid - 2464) * 256 + tid;
        int j = tt & 7, lane = (tt >> 3) & 63, rest = tt >> 9;
        int mt = rest & 7, step = rest >> 3;
        int oc = mt * 16 + (lane & 15);
        int k = step * 32 + ((lane >> 4) << 3) + j;
        int dk = k >> 6, c = k & 63;
        int d = (dk >= 9) ? 1 : 0;
        int kk = dk - d * 9;
        wfD[tt] = f2b(dc_w[((size_t)oc * 128 + d * 64 + c) * 9 + kk]);
        return;
    }
    {                                       // ---- cv2 repack: k = c ----
        int tt = (bid - 3040) * 256 + tid;
        int j = tt & 7, lane = (tt >> 3) & 63, rest = tt >> 9;
        int mt = rest & 7, step = rest >> 3;
        int oc = mt * 16 + (lane & 15);
        int k = step * 32 + ((lane >> 4) << 3) + j;
        wfC[tt] = f2b(cv2_w[oc * 128 + k]);
    }
}

// ---------------------------------------------------------------------------
// 3x3 conv, implicit GEMM, 128 px (full row) x (NMT*32) oc per block.
// K in FOUR 32-ch phases, double-buffered LDS (2 x 15.6 KB = 31.2 KB):
//   phase p: issue load(p+1) [lands during compute], compute(p) on buf p&1,
//            write load -> buf (p+1)&1, sync.   (1 barrier/phase)
// Writes target the buffer NOT being read -> staging loads stay in flight
// across the whole compute phase. __launch_bounds__(256,3): 3 blocks/CU.
// [Structure from R6 — exonerated by the R7 bisect; R6's failure was the
//  type-punned blend in deform, not this kernel.]
// MODE 0: +bias -> fp32 NCHW [B][54][HW]   (offset conv, NMT=2)
// MODE 1: +bias,BN,ReLU -> bf16 NHWC
// MODE 2: +bias,BN,+res(bf16 NHWC),ReLU -> bf16 NHWC
// ---------------------------------------------------------------------------
template<int NMT, int MODE>
__global__ __launch_bounds__(256, 3) void conv3x3_mfma(
    const unsigned short* __restrict__ in, const unsigned short* __restrict__ wf,
    const float* __restrict__ bias, const float* __restrict__ bnp,
    const unsigned short* __restrict__ res, void* __restrict__ outv)
{
    __shared__ unsigned short sm[2][3][130][40];
    const int tid = threadIdx.x;
    const int lane = tid & 63, wid = tid >> 6;
    const int wm = wid & 1, wn = wid >> 1;
    const int h = blockIdx.x;
    const int b = blockIdx.y;
    const int n16 = lane & 15, quad = lane >> 4;

    short8 L[7];
    // 1560 16B-chunks per phase: idx -> (r, wl, c8), c8 in [0,4)
    auto stage_load = [&](int phase) {
#pragma unroll
        for (int rnd = 0; rnd < 7; ++rnd) {
            int idx = rnd * 256 + tid;
            short8 v = {0, 0, 0, 0, 0, 0, 0, 0};
            if (idx < 1560) {
                int c8 = idx & 3;
                int wl = (idx >> 2) % 130;
                int r  = (idx >> 2) / 130;
                int hh = h - 1 + r, ww = wl - 1;
                if ((unsigned)hh < 128u && (unsigned)ww < 128u)
                    v = *(const short8*)&in[(((size_t)b << 14) + hh * 128 + ww) * 128 + phase * 32 + c8 * 8];
            }
            L[rnd] = v;
        }
    };
    auto stage_write = [&](int buf) {
#pragma unroll
        for (int rnd = 0; rnd < 7; ++rnd) {
            int idx = rnd * 256 + tid;
            if (idx < 1560) {
                int c8 = idx & 3;
                int wl = (idx >> 2) % 130;
                int r  = (idx >> 2) / 130;
                *(short8*)&sm[buf][r][wl][c8 * 8] = L[rnd];
            }
        }
    };

    floatx4 acc[NMT][4];
#pragma unroll
    for (int mt = 0; mt < NMT; ++mt)
#pragma unroll
        for (int nt = 0; nt < 4; ++nt)
            acc[mt][nt] = (floatx4){0.f, 0.f, 0.f, 0.f};

    auto compute = [&](int phase, int buf) {
#pragma unroll
        for (int tap = 0; tap < 9; ++tap) {
            const int ky = tap / 3, kx = tap % 3;
            const int step = phase * 9 + tap;
            short8 a[NMT], bf[4];
#pragma unroll
            for (int nt = 0; nt < 4; ++nt)
                bf[nt] = *(const short8*)&sm[buf][ky][wn * 64 + nt * 16 + n16 + kx][quad * 8];
#pragma unroll
            for (int mt = 0; mt < NMT; ++mt)
                a[mt] = *(const short8*)&wf[((size_t)(step * (2 * NMT) + wm * NMT + mt) * 64 + lane) * 8];
#pragma unroll
            for (int mt = 0; mt < NMT; ++mt)
#pragma unroll
                for (int nt = 0; nt < 4; ++nt)
                    acc[mt][nt] = __builtin_amdgcn_mfma_f32_16x16x32_bf16(a[mt], bf[nt], acc[mt][nt], 0, 0, 0);
        }
    };

    stage_load(0);
    stage_write(0);
    __syncthreads();
#pragma unroll
    for (int p = 0; p < 4; ++p) {
        if (p < 3) stage_load(p + 1);     // loads fly during compute(p)
        compute(p, p & 1);
        if (p < 3) {
            stage_write((p + 1) & 1);     // other buffer: no read hazard
            __syncthreads();
        }
    }

    // epilogue
#pragma unroll
    for (int mt = 0; mt < NMT; ++mt) {
        const int ocb = (wm * NMT + mt) * 16 + quad * 4;
        float Ae[4], Be[4];
#pragma unroll
        for (int r = 0; r < 4; ++r) {
            int oc = ocb + r;
            if (MODE == 0) {
                Ae[r] = 1.f;
                Be[r] = (oc < 54) ? bias[oc] : 0.f;
            } else {
                float g = bnp[oc], be = bnp[128 + oc], m = bnp[256 + oc], vv = bnp[384 + oc];
                float inv = g * rsqrtf(vv + EPSV);
                Ae[r] = inv;
                Be[r] = be - m * inv + bias[oc] * inv;
            }
        }
#pragma unroll
        for (int nt = 0; nt < 4; ++nt) {
            int pxg = h * 128 + wn * 64 + nt * 16 + n16;
            if (MODE == 0) {
                float* outf = (float*)outv;   // NCHW [B][54][HW]
#pragma unroll
                for (int r = 0; r < 4; ++r) {
                    int oc = ocb + r;
                    if (oc < 54)
                        outf[(((size_t)(b * 54 + oc)) << 14) + pxg] = acc[mt][nt][r] + Be[r];
                }
            } else {
                ushort4v rv = {0, 0, 0, 0};
                if (MODE == 2)
                    rv = *(const ushort4v*)&res[((size_t)((b << 14) + pxg)) * 128 + ocb];
                ushort4v pk;
#pragma unroll
                for (int r = 0; r < 4; ++r) {
                    float v = acc[mt][nt][r] * Ae[r] + Be[r];
                    if (MODE == 2) v += b2f(rv[r]);
                    v = fmaxf(v, 0.f);
                    pk[r] = f2b(v);
                }
                *(ushort4v*)&((unsigned short*)outv)[((size_t)((b << 14) + pxg)) * 128 + ocb] = pk;
            }
        }
    }
}

// ---------------------------------------------------------------------------
// Fused modulated deformable conv + BN(bn1) + LeakyReLU + 1x1 conv + BN(bn2)
// + LeakyReLU + residual(xb bf16) -> fp32 NCHW d_out.
// Deform part: R8-proven (wave-0 sampling math, coalesced corner gather,
// scalar blend, double-buffered B-tile, 1 barrier/dk). Its bf16 output tile
// (64 px x 128 oc) goes to LDS `ot`, then the K=128 1x1 GEMM consumes it —
// h3 never touches global (saves ~33 MB round trip + one launch).
// Block = 128 oc x 64 px. LDS: 18 + 6 + 17.4 = 41.4 KB -> 3 blocks/CU.
// ---------------------------------------------------------------------------
__global__ __launch_bounds__(256, 3) void deform_fused(
    const unsigned short* __restrict__ src, const float* __restrict__ off,
    const unsigned short* __restrict__ wf, const float* __restrict__ dcb,
    const float* __restrict__ bnp1, const unsigned short* __restrict__ wfC,
    const float* __restrict__ bnp2, const unsigned short* __restrict__ xres,
    float* __restrict__ out)
{
    __shared__ unsigned short gt[2][64][72];   // 18 KB   deform B-tiles
    __shared__ floatx4 smw[3][64];             // 3 KB    blend weights
    __shared__ intx4   sma[3][64];             // 3 KB    corner byte offsets
    __shared__ unsigned short ot[64][136];     // 17.4 KB deform output tile
    const int tid = threadIdx.x;
    const int lane = tid & 63, wid = tid >> 6;
    const int wm = wid & 1, wn = wid >> 1;
    const int w0 = (blockIdx.x & 1) * 64;
    const int h = blockIdx.x >> 1;
    const int b = blockIdx.y;
    const int n16 = lane & 15, quad = lane >> 4;
    const int q = tid & 7;
    const int pxq = (tid >> 3) & 31;

    const char* srcbyte = (const char*)src + ((size_t)b << 22);
    const float* offpx = off + (((size_t)(b * 54)) << 14) + h * 128 + w0 + tid; // tid<64 only

    auto math = [&](int dk, int slot) {
        float oy = offpx[(size_t)(2 * dk) << 14];
        float ox = offpx[(size_t)(2 * dk + 1) << 14];
        float mz = offpx[(size_t)(36 + dk) << 14];
        int d = (dk >= 9) ? 1 : 0;
        int kk = dk - d * 9;
        float ms = 1.f / (1.f + __expf(-mz));
        float py = oy + (float)h + (float)(kk / 3 - 1);
        float pxs = ox + (float)(w0 + tid) + (float)(kk % 3 - 1);
        float y0f = floorf(py), x0f = floorf(pxs);
        float fy = py - y0f, fx = pxs - x0f;
        int y0 = (int)y0f, x0 = (int)x0f;
        int y1 = y0 + 1, x1 = x0 + 1;
        float w00 = (1.f - fy) * (1.f - fx) * ms, w01 = (1.f - fy) * fx * ms;
        float w10 = fy * (1.f - fx) * ms, w11 = fy * fx * ms;
        if ((unsigned)y0 >= 128u) { w00 = 0.f; w01 = 0.f; }
        if ((unsigned)y1 >= 128u) { w10 = 0.f; w11 = 0.f; }
        if ((unsigned)x0 >= 128u) { w00 = 0.f; w10 = 0.f; }
        if ((unsigned)x1 >= 128u) { w01 = 0.f; w11 = 0.f; }
        int y0c = min(max(y0, 0), 127), y1c = min(max(y1, 0), 127);
        int x0c = min(max(x0, 0), 127), x1c = min(max(x1, 0), 127);
        int chb = d * 128;
        smw[slot][tid] = (floatx4){w00, w01, w10, w11};
        sma[slot][tid] = (intx4){((y0c * 128 + x0c) << 8) + chb, ((y0c * 128 + x1c) << 8) + chb,
                                 ((y1c * 128 + x0c) << 8) + chb, ((y1c * 128 + x1c) << 8) + chb};
    };

    floatx4 wA[2];
    short8 g[2][4];
    auto gather = [&](int slot) {
#pragma unroll
        for (int ph = 0; ph < 2; ++ph) {
            int pxl = ph * 32 + pxq;
            floatx4 wv = smw[slot][pxl];
            intx4 av = sma[slot][pxl];
            wA[ph] = wv;
#pragma unroll
            for (int c = 0; c < 4; ++c)
                g[ph][c] = *(const short8*)(srcbyte + (size_t)(av[c] + q * 16));
        }
    };

    floatx4 acc[4][2];
#pragma unroll
    for (int mt = 0; mt < 4; ++mt)
#pragma unroll
        for (int nt = 0; nt < 2; ++nt)
            acc[mt][nt] = (floatx4){0.f, 0.f, 0.f, 0.f};

    if (tid < 64) { math(0, 0); math(1, 1); }
    __syncthreads();
    gather(0);

    int buf = 0;
    for (int dk = 0; dk < 18; ++dk) {
        // scalar blend of prefetched corners -> LDS B-tile (R8-proven)
#pragma unroll
        for (int ph = 0; ph < 2; ++ph) {
            short8 o8;
#pragma unroll
            for (int j = 0; j < 8; ++j) {
                float v = wA[ph][0] * b2f((unsigned short)g[ph][0][j])
                        + wA[ph][1] * b2f((unsigned short)g[ph][1][j])
                        + wA[ph][2] * b2f((unsigned short)g[ph][2][j])
                        + wA[ph][3] * b2f((unsigned short)g[ph][3][j]);
                o8[j] = (short)f2b_fast(v);
            }
            *(short8*)&gt[buf][ph * 32 + pxq][q * 8] = o8;
        }
        if (tid < 64 && dk < 16) math(dk + 2, (dk + 2) % 3);
        __syncthreads();
        if (dk < 17) gather((dk + 1) % 3);

#pragma unroll
        for (int hf = 0; hf < 2; ++hf) {
            int s = dk * 2 + hf;
            short8 a[4], bfr[2];
#pragma unroll
            for (int nt = 0; nt < 2; ++nt)
                bfr[nt] = *(const short8*)&gt[buf][wn * 32 + nt * 16 + n16][hf * 32 + quad * 8];
#pragma unroll
            for (int mt = 0; mt < 4; ++mt)
                a[mt] = *(const short8*)&wf[((size_t)(s * 8 + wm * 4 + mt) * 64 + lane) * 8];
#pragma unroll
            for (int mt = 0; mt < 4; ++mt)
#pragma unroll
                for (int nt = 0; nt < 2; ++nt)
                    acc[mt][nt] = __builtin_amdgcn_mfma_f32_16x16x32_bf16(a[mt], bfr[nt], acc[mt][nt], 0, 0, 0);
        }
        buf ^= 1;
    }

    // deform epilogue: +dc_b, BN(bn1), LeakyReLU -> bf16 tile in LDS
#pragma unroll
    for (int mt = 0; mt < 4; ++mt) {
        const int ocb = (wm * 4 + mt) * 16 + quad * 4;
        float Ae[4], Be[4];
#pragma unroll
        for (int r = 0; r < 4; ++r) {
            int oc = ocb + r;
            float gg = bnp1[oc], be = bnp1[128 + oc], m = bnp1[256 + oc], vv = bnp1[384 + oc];
            float inv = gg * rsqrtf(vv + EPSV);
            Ae[r] = inv;
            Be[r] = be - m * inv + dcb[oc] * inv;
        }
#pragma unroll
        for (int nt = 0; nt < 2; ++nt) {
            int pxl = wn * 32 + nt * 16 + n16;
            ushort4v pk;
#pragma unroll
            for (int r = 0; r < 4; ++r) {
                float v = acc[mt][nt][r] * Ae[r] + Be[r];
                v = (v > 0.f) ? v : 0.1f * v;
                pk[r] = f2b(v);
            }
            *(ushort4v*)&ot[pxl][ocb] = pk;
        }
    }
    __syncthreads();

    // ---- fused 1x1 conv: K=128 from LDS tile ----
    floatx4 acc1[4][2];
#pragma unroll
    for (int mt = 0; mt < 4; ++mt)
#pragma unroll
        for (int nt = 0; nt < 2; ++nt)
            acc1[mt][nt] = (floatx4){0.f, 0.f, 0.f, 0.f};

#pragma unroll
    for (int s = 0; s < 4; ++s) {
        short8 a[4], bfr[2];
#pragma unroll
        for (int nt = 0; nt < 2; ++nt)
            bfr[nt] = *(const short8*)&ot[wn * 32 + nt * 16 + n16][s * 32 + quad * 8];
#pragma unroll
        for (int mt = 0; mt < 4; ++mt)
            a[mt] = *(const short8*)&wfC[((size_t)(s * 8 + wm * 4 + mt) * 64 + lane) * 8];
#pragma unroll
        for (int mt = 0; mt < 4; ++mt)
#pragma unroll
            for (int nt = 0; nt < 2; ++nt)
                acc1[mt][nt] = __builtin_amdgcn_mfma_f32_16x16x32_bf16(a[mt], bfr[nt], acc1[mt][nt], 0, 0, 0);
    }

#pragma unroll
    for (int mt = 0; mt < 4; ++mt) {
        const int ocb = (wm * 4 + mt) * 16 + quad * 4;
        float Ae[4], Be[4];
#pragma unroll
        for (int r = 0; r < 4; ++r) {
            int oc = ocb + r;
            float gg = bnp2[oc], be = bnp2[128 + oc], m = bnp2[256 + oc], vv = bnp2[384 + oc];
            float inv = gg * rsqrtf(vv + EPSV);
            Ae[r] = inv;
            Be[r] = be - m * inv;
        }
#pragma unroll
        for (int nt = 0; nt < 2; ++nt) {
            int pxg2 = h * 128 + w0 + wn * 32 + nt * 16 + n16;
            ushort4v rv = *(const ushort4v*)&xres[((size_t)((b << 14) + pxg2)) * 128 + ocb];
#pragma unroll
            for (int r = 0; r < 4; ++r) {
                int oc = ocb + r;
                float v = acc1[mt][nt][r] * Ae[r] + Be[r];
                v = (v > 0.f) ? v : 0.1f * v;
                v += b2f(rv[r]);
                out[(((size_t)b * 128 + oc) << 14) + pxg2] = v;
            }
        }
    }
}

// ---------------------------------------------------------------------------
extern "C" void kernel_launch(void* const* d_in, const int* in_sizes, int n_in,
                              void* d_out, int out_size, void* d_ws, size_t ws_size,
                              hipStream_t stream) {
    const float* x      = (const float*)d_in[0];
    const float* rb_w1  = (const float*)d_in[1];
    const float* rb_b1  = (const float*)d_in[2];
    const float* rb_bn1 = (const float*)d_in[3];
    const float* rb_w2  = (const float*)d_in[4];
    const float* rb_b2  = (const float*)d_in[5];
    const float* rb_bn2 = (const float*)d_in[6];
    const float* off_w  = (const float*)d_in[7];
    const float* off_b  = (const float*)d_in[8];
    const float* dc_w   = (const float*)d_in[9];
    const float* dc_b   = (const float*)d_in[10];
    const float* bn1    = (const float*)d_in[11];
    const float* cv2_w  = (const float*)d_in[12];
    const float* bn2    = (const float*)d_in[13];

    char* base = (char*)d_ws;
    const size_t TSZ = (size_t)4 * 16384 * 128 * 2;       // 16.78 MB bf16 tensor
    unsigned short* xb = (unsigned short*)base;            // stays live (residuals)
    unsigned short* h1 = (unsigned short*)(base + TSZ);    // aliased later as offb
    unsigned short* h2 = (unsigned short*)(base + 2 * TSZ);
    unsigned short* wf1 = (unsigned short*)(base + 3 * TSZ);
    unsigned short* wf2 = wf1 + 1152 * 128;
    unsigned short* wfO = wf2 + 1152 * 128;
    unsigned short* wfD = wfO + 1152 * 64;
    unsigned short* wfC = wfD + 1152 * 128;
    float* offb = (float*)h1;            // NCHW fp32 [B][54][HW], 14.16 MB <= TSZ

    dim3 blk(256, 1, 1);
    dim3 grid(256, BB, 1);
    dim3 grid3(128, BB, 1);

    prep_k<<<3104, 256, 0, stream>>>(x, xb, rb_w1, wf1, rb_w2, wf2,
                                     off_w, wfO, dc_w, wfD, cv2_w, wfC);

    // ResBlock
    conv3x3_mfma<4, 1><<<grid3, blk, 0, stream>>>(xb, wf1, rb_b1, rb_bn1, nullptr, (void*)h1);
    conv3x3_mfma<4, 2><<<grid3, blk, 0, stream>>>(h1, wf2, rb_b2, rb_bn2, xb, (void*)h2);
    // offset conv -> NCHW fp32 (writes over h1, which is dead)
    conv3x3_mfma<2, 0><<<grid3, blk, 0, stream>>>(h2, wfO, off_b, nullptr, nullptr, (void*)offb);
    // fused deformable conv + BN + LeakyReLU + 1x1 conv + BN + LeakyReLU + residual
    deform_fused<<<grid, blk, 0, stream>>>(h2, offb, wfD, dc_b, bn1, wfC, bn2, xb, (float*)d_out);
}

// Round 10
// 248.571 us; speedup vs baseline: 1.1035x; 1.1035x over previous
//
#include <hip/hip_runtime.h>
#include <math.h>

#define BB 4
#define EPSV 1e-5f

typedef __attribute__((ext_vector_type(8))) short short8;
typedef __attribute__((ext_vector_type(4))) float floatx4;
typedef __attribute__((ext_vector_type(4))) int intx4;
typedef __attribute__((ext_vector_type(4))) unsigned short ushort4v;

__device__ inline float b2f(unsigned short u) {
    unsigned v = ((unsigned)u) << 16;
    return __builtin_bit_cast(float, v);
}
__device__ inline unsigned short f2b(float f) {   // RNE
    unsigned u = __builtin_bit_cast(unsigned, f);
    u += 0x7FFFu + ((u >> 16) & 1u);
    return (unsigned short)(u >> 16);
}
__device__ inline unsigned short f2b_fast(float f) {  // round-half-up, 2 inst
    unsigned u = __builtin_bit_cast(unsigned, f);
    return (unsigned short)((u + 0x8000u) >> 16);
}

// ---------------------------------------------------------------------------
// Fused prep kernel: transpose + all 5 weight repacks in ONE launch.
// blockIdx.x ranges:
//   [0,1024)     : transpose x (fp32 NCHW) -> xb (bf16 NHWC)
//   [1024,1600)  : repack rb_w1 -> wf1   (conv frag, MPAD=128)
//   [1600,2176)  : repack rb_w2 -> wf2
//   [2176,2464)  : repack off_w -> wfO   (conv frag, MPAD=64, OCH=54)
//   [2464,3040)  : repack dc_w  -> wfD
//   [3040,3104)  : repack cv2_w -> wfC
// Weight frag order: dst[((step*NMT2+mt)*64+lane)*8+j] = W[oc][k],
//   oc = mt*16+(lane&15), k = step*32+(lane>>4)*8+j.
// conv3x3 K-order (R4/R8-proven two-half): half = k/576,
//   tap = (k-half*576)>>6, c = half*64 + (k&63)
//   [consumer: step = half*18 + tap*2 + cc]
// ---------------------------------------------------------------------------
__global__ __launch_bounds__(256) void prep_k(
    const float* __restrict__ x, unsigned short* __restrict__ xb,
    const float* __restrict__ rb_w1, unsigned short* __restrict__ wf1,
    const float* __restrict__ rb_w2, unsigned short* __restrict__ wf2,
    const float* __restrict__ off_w, unsigned short* __restrict__ wfO,
    const float* __restrict__ dc_w, unsigned short* __restrict__ wfD,
    const float* __restrict__ cv2_w, unsigned short* __restrict__ wfC)
{
    __shared__ unsigned short t[64][136];
    const int bid = blockIdx.x;
    const int tid = threadIdx.x;

    if (bid < 1024) {                       // ---- transpose ----
        const int px0 = (bid & 255) * 64;
        const int b = bid >> 8;
        const int pxr = tid & 63;
        const int c0 = tid >> 6;
#pragma unroll
        for (int i = 0; i < 32; ++i) {
            int c = c0 + i * 4;
            float v = x[(((size_t)b * 128 + c) << 14) + px0 + pxr];
            t[pxr][c] = f2b(v);
        }
        __syncthreads();
#pragma unroll
        for (int i = 0; i < 4; ++i) {
            int idx = tid + i * 256;
            int px = idx >> 4;
            int c8 = idx & 15;
            short8 v = *(const short8*)&t[px][c8 * 8];
            *(short8*)&xb[(((size_t)b << 14) + px0 + px) * 128 + c8 * 8] = v;
        }
        return;
    }
    if (bid < 2464) {                       // ---- conv-frag repacks (two-half K-order) ----
        const float* w; unsigned short* dst; int MPAD, OCH, t0;
        if (bid < 1600)      { w = rb_w1; dst = wf1; MPAD = 128; OCH = 128; t0 = 1024; }
        else if (bid < 2176) { w = rb_w2; dst = wf2; MPAD = 128; OCH = 128; t0 = 1600; }
        else                 { w = off_w; dst = wfO; MPAD = 64;  OCH = 54;  t0 = 2176; }
        int tt = (bid - t0) * 256 + tid;
        if (tt >= 1152 * MPAD) return;
        const int NMT2 = MPAD / 16;
        int j = tt & 7, lane = (tt >> 3) & 63, rest = tt >> 9;
        int mt = rest % NMT2, step = rest / NMT2;
        int oc = mt * 16 + (lane & 15);
        int k = step * 32 + ((lane >> 4) << 3) + j;
        int half = k / 576;
        int tap = (k - half * 576) >> 6;
        int c = half * 64 + (k & 63);
        float v = (oc < OCH) ? w[((size_t)oc * 128 + c) * 9 + tap] : 0.f;
        dst[tt] = f2b(v);
        return;
    }
    if (bid < 3040) {                       // ---- dc repack: k = dk*64+c ----
        int tt = (bid - 2464) * 256 + tid;
        int j = tt & 7, lane = (tt >> 3) & 63, rest = tt >> 9;
        int mt = rest & 7, step = rest >> 3;
        int oc = mt * 16 + (lane & 15);
        int k = step * 32 + ((lane >> 4) << 3) + j;
        int dk = k >> 6, c = k & 63;
        int d = (dk >= 9) ? 1 : 0;
        int kk = dk - d * 9;
        wfD[tt] = f2b(dc_w[((size_t)oc * 128 + d * 64 + c) * 9 + kk]);
        return;
    }
    {                                       // ---- cv2 repack: k = c ----
        int tt = (bid - 3040) * 256 + tid;
        int j = tt & 7, lane = (tt >> 3) & 63, rest = tt >> 9;
        int mt = rest & 7, step = rest >> 3;
        int oc = mt * 16 + (lane & 15);
        int k = step * 32 + ((lane >> 4) << 3) + j;
        wfC[tt] = f2b(cv2_w[oc * 128 + k]);
    }
}

// ---------------------------------------------------------------------------
// 3x3 conv, implicit GEMM, 128-px (full row) x (NMT*32) oc tile.
// [EXACT R4/R8-proven structure — the R9 4-phase variant measured ~5 µs/conv
//  slower (more barriers, occupancy still grid-capped at 2 blocks/CU).]
// 4 waves in 2x2: wm = M-half, wn = N-half (64 px each).
// K split in two 64-ch halves; half-1 staging prefetched into registers
// before half-0 compute (loads in flight across compute(0)).
// LDS: 3 rows x 130 w x 64 ch (stride 72) = 54.8 KB -> 2 blocks/CU.
// MODE 0: +bias -> fp32 NCHW [B][54][HW]   (offset conv, NMT=2)
// MODE 1: +bias,BN,ReLU -> bf16 NHWC
// MODE 2: +bias,BN,+res(bf16 NHWC),ReLU -> bf16 NHWC
// ---------------------------------------------------------------------------
template<int NMT, int MODE>
__global__ __launch_bounds__(256, 2) void conv3x3_mfma(
    const unsigned short* __restrict__ in, const unsigned short* __restrict__ wf,
    const float* __restrict__ bias, const float* __restrict__ bnp,
    const unsigned short* __restrict__ res, void* __restrict__ outv)
{
    __shared__ unsigned short sm[3][130][72];
    const int tid = threadIdx.x;
    const int lane = tid & 63, wid = tid >> 6;
    const int wm = wid & 1, wn = wid >> 1;
    const int h = blockIdx.x;
    const int b = blockIdx.y;
    const int n16 = lane & 15, quad = lane >> 4;

    short8 L[13];

    auto stage_load = [&](int half) {
#pragma unroll
        for (int rnd = 0; rnd < 13; ++rnd) {
            int idx = rnd * 256 + tid;
            short8 v = {0, 0, 0, 0, 0, 0, 0, 0};
            if (idx < 3120) {
                int c8 = idx & 7;
                int wl = (idx >> 3) % 130;
                int r  = (idx >> 3) / 130;
                int hh = h - 1 + r, ww = wl - 1;
                if ((unsigned)hh < 128u && (unsigned)ww < 128u)
                    v = *(const short8*)&in[(((size_t)b << 14) + hh * 128 + ww) * 128 + half * 64 + c8 * 8];
            }
            L[rnd] = v;
        }
    };
    auto stage_write = [&]() {
#pragma unroll
        for (int rnd = 0; rnd < 13; ++rnd) {
            int idx = rnd * 256 + tid;
            if (idx < 3120) {
                int c8 = idx & 7;
                int wl = (idx >> 3) % 130;
                int r  = (idx >> 3) / 130;
                *(short8*)&sm[r][wl][c8 * 8] = L[rnd];
            }
        }
    };

    floatx4 acc[NMT][4];
#pragma unroll
    for (int mt = 0; mt < NMT; ++mt)
#pragma unroll
        for (int nt = 0; nt < 4; ++nt)
            acc[mt][nt] = (floatx4){0.f, 0.f, 0.f, 0.f};

    auto compute = [&](int half) {
#pragma unroll
        for (int tap = 0; tap < 9; ++tap) {
            const int ky = tap / 3, kx = tap % 3;
#pragma unroll
            for (int cc = 0; cc < 2; ++cc) {
                const int step = half * 18 + tap * 2 + cc;
                short8 a[NMT], bf[4];
#pragma unroll
                for (int nt = 0; nt < 4; ++nt)
                    bf[nt] = *(const short8*)&sm[ky][wn * 64 + nt * 16 + n16 + kx][cc * 32 + quad * 8];
#pragma unroll
                for (int mt = 0; mt < NMT; ++mt)
                    a[mt] = *(const short8*)&wf[((size_t)(step * (2 * NMT) + wm * NMT + mt) * 64 + lane) * 8];
#pragma unroll
                for (int mt = 0; mt < NMT; ++mt)
#pragma unroll
                    for (int nt = 0; nt < 4; ++nt)
                        acc[mt][nt] = __builtin_amdgcn_mfma_f32_16x16x32_bf16(a[mt], bf[nt], acc[mt][nt], 0, 0, 0);
            }
        }
    };

    stage_load(0);
    stage_write();
    __syncthreads();
    stage_load(1);       // VMEM in flight across half-0 compute
    compute(0);
    __syncthreads();     // all waves done reading half-0 LDS
    stage_write();
    __syncthreads();
    compute(1);

    // epilogue
#pragma unroll
    for (int mt = 0; mt < NMT; ++mt) {
        const int ocb = (wm * NMT + mt) * 16 + quad * 4;
        float Ae[4], Be[4];
#pragma unroll
        for (int r = 0; r < 4; ++r) {
            int oc = ocb + r;
            if (MODE == 0) {
                Ae[r] = 1.f;
                Be[r] = (oc < 54) ? bias[oc] : 0.f;
            } else {
                float g = bnp[oc], be = bnp[128 + oc], m = bnp[256 + oc], vv = bnp[384 + oc];
                float inv = g * rsqrtf(vv + EPSV);
                Ae[r] = inv;
                Be[r] = be - m * inv + bias[oc] * inv;
            }
        }
#pragma unroll
        for (int nt = 0; nt < 4; ++nt) {
            int pxg = h * 128 + wn * 64 + nt * 16 + n16;
            if (MODE == 0) {
                float* outf = (float*)outv;   // NCHW [B][54][HW]
#pragma unroll
                for (int r = 0; r < 4; ++r) {
                    int oc = ocb + r;
                    if (oc < 54)
                        outf[(((size_t)(b * 54 + oc)) << 14) + pxg] = acc[mt][nt][r] + Be[r];
                }
            } else {
                ushort4v rv = {0, 0, 0, 0};
                if (MODE == 2)
                    rv = *(const ushort4v*)&res[((size_t)((b << 14) + pxg)) * 128 + ocb];
                ushort4v pk;
#pragma unroll
                for (int r = 0; r < 4; ++r) {
                    float v = acc[mt][nt][r] * Ae[r] + Be[r];
                    if (MODE == 2) v += b2f(rv[r]);
                    v = fmaxf(v, 0.f);
                    pk[r] = f2b(v);
                }
                *(ushort4v*)&((unsigned short*)outv)[((size_t)((b << 14) + pxg)) * 128 + ocb] = pk;
            }
        }
    }
}

// ---------------------------------------------------------------------------
// Fused modulated deformable conv + BN(bn1) + LeakyReLU + 1x1 conv + BN(bn2)
// + LeakyReLU + residual(xb bf16) -> fp32 NCHW d_out.
// R9-proven structure; R10 change: the deform output tile `ot` now OVERLAYS
// gt's storage (gt is dead after the K-loop; same element type, explicit
// __syncthreads between last gt read and first ot write). LDS 41,984 ->
// 24,576 B; __launch_bounds__(256,4) -> 4 blocks/CU (grid allows exactly 4).
// Block = 128 oc x 64 px.
// ---------------------------------------------------------------------------
__global__ __launch_bounds__(256, 4) void deform_fused(
    const unsigned short* __restrict__ src, const float* __restrict__ off,
    const unsigned short* __restrict__ wf, const float* __restrict__ dcb,
    const float* __restrict__ bnp1, const unsigned short* __restrict__ wfC,
    const float* __restrict__ bnp2, const unsigned short* __restrict__ xres,
    float* __restrict__ out)
{
    __shared__ unsigned short gt[2][64][72];   // 18,432 B  deform B-tiles; reused as ot
    __shared__ floatx4 smw[3][64];             // 3 KB  blend weights
    __shared__ intx4   sma[3][64];             // 3 KB  corner byte offsets
    // ot overlays gt: 64 x 136 shorts = 17,408 B <= 18,432 B
    unsigned short (*ot)[136] = reinterpret_cast<unsigned short(*)[136]>(&gt[0][0][0]);
    const int tid = threadIdx.x;
    const int lane = tid & 63, wid = tid >> 6;
    const int wm = wid & 1, wn = wid >> 1;
    const int w0 = (blockIdx.x & 1) * 64;
    const int h = blockIdx.x >> 1;
    const int b = blockIdx.y;
    const int n16 = lane & 15, quad = lane >> 4;
    const int q = tid & 7;
    const int pxq = (tid >> 3) & 31;

    const char* srcbyte = (const char*)src + ((size_t)b << 22);
    const float* offpx = off + (((size_t)(b * 54)) << 14) + h * 128 + w0 + tid; // tid<64 only

    auto math = [&](int dk, int slot) {
        float oy = offpx[(size_t)(2 * dk) << 14];
        float ox = offpx[(size_t)(2 * dk + 1) << 14];
        float mz = offpx[(size_t)(36 + dk) << 14];
        int d = (dk >= 9) ? 1 : 0;
        int kk = dk - d * 9;
        float ms = 1.f / (1.f + __expf(-mz));
        float py = oy + (float)h + (float)(kk / 3 - 1);
        float pxs = ox + (float)(w0 + tid) + (float)(kk % 3 - 1);
        float y0f = floorf(py), x0f = floorf(pxs);
        float fy = py - y0f, fx = pxs - x0f;
        int y0 = (int)y0f, x0 = (int)x0f;
        int y1 = y0 + 1, x1 = x0 + 1;
        float w00 = (1.f - fy) * (1.f - fx) * ms, w01 = (1.f - fy) * fx * ms;
        float w10 = fy * (1.f - fx) * ms, w11 = fy * fx * ms;
        if ((unsigned)y0 >= 128u) { w00 = 0.f; w01 = 0.f; }
        if ((unsigned)y1 >= 128u) { w10 = 0.f; w11 = 0.f; }
        if ((unsigned)x0 >= 128u) { w00 = 0.f; w10 = 0.f; }
        if ((unsigned)x1 >= 128u) { w01 = 0.f; w11 = 0.f; }
        int y0c = min(max(y0, 0), 127), y1c = min(max(y1, 0), 127);
        int x0c = min(max(x0, 0), 127), x1c = min(max(x1, 0), 127);
        int chb = d * 128;
        smw[slot][tid] = (floatx4){w00, w01, w10, w11};
        sma[slot][tid] = (intx4){((y0c * 128 + x0c) << 8) + chb, ((y0c * 128 + x1c) << 8) + chb,
                                 ((y1c * 128 + x0c) << 8) + chb, ((y1c * 128 + x1c) << 8) + chb};
    };

    floatx4 wA[2];
    short8 g[2][4];
    auto gather = [&](int slot) {
#pragma unroll
        for (int ph = 0; ph < 2; ++ph) {
            int pxl = ph * 32 + pxq;
            floatx4 wv = smw[slot][pxl];
            intx4 av = sma[slot][pxl];
            wA[ph] = wv;
#pragma unroll
            for (int c = 0; c < 4; ++c)
                g[ph][c] = *(const short8*)(srcbyte + (size_t)(av[c] + q * 16));
        }
    };

    floatx4 acc[4][2];
#pragma unroll
    for (int mt = 0; mt < 4; ++mt)
#pragma unroll
        for (int nt = 0; nt < 2; ++nt)
            acc[mt][nt] = (floatx4){0.f, 0.f, 0.f, 0.f};

    if (tid < 64) { math(0, 0); math(1, 1); }
    __syncthreads();
    gather(0);

    int buf = 0;
    for (int dk = 0; dk < 18; ++dk) {
        // scalar blend of prefetched corners -> LDS B-tile (R8-proven)
#pragma unroll
        for (int ph = 0; ph < 2; ++ph) {
            short8 o8;
#pragma unroll
            for (int j = 0; j < 8; ++j) {
                float v = wA[ph][0] * b2f((unsigned short)g[ph][0][j])
                        + wA[ph][1] * b2f((unsigned short)g[ph][1][j])
                        + wA[ph][2] * b2f((unsigned short)g[ph][2][j])
                        + wA[ph][3] * b2f((unsigned short)g[ph][3][j]);
                o8[j] = (short)f2b_fast(v);
            }
            *(short8*)&gt[buf][ph * 32 + pxq][q * 8] = o8;
        }
        if (tid < 64 && dk < 16) math(dk + 2, (dk + 2) % 3);
        __syncthreads();
        if (dk < 17) gather((dk + 1) % 3);

#pragma unroll
        for (int hf = 0; hf < 2; ++hf) {
            int s = dk * 2 + hf;
            short8 a[4], bfr[2];
#pragma unroll
            for (int nt = 0; nt < 2; ++nt)
                bfr[nt] = *(const short8*)&gt[buf][wn * 32 + nt * 16 + n16][hf * 32 + quad * 8];
#pragma unroll
            for (int mt = 0; mt < 4; ++mt)
                a[mt] = *(const short8*)&wf[((size_t)(s * 8 + wm * 4 + mt) * 64 + lane) * 8];
#pragma unroll
            for (int mt = 0; mt < 4; ++mt)
#pragma unroll
                for (int nt = 0; nt < 2; ++nt)
                    acc[mt][nt] = __builtin_amdgcn_mfma_f32_16x16x32_bf16(a[mt], bfr[nt], acc[mt][nt], 0, 0, 0);
        }
        buf ^= 1;
    }

    // gt is dead from here; ot overlays it — drain all gt reads first.
    __syncthreads();

    // deform epilogue: +dc_b, BN(bn1), LeakyReLU -> bf16 tile in LDS (ot)
#pragma unroll
    for (int mt = 0; mt < 4; ++mt) {
        const int ocb = (wm * 4 + mt) * 16 + quad * 4;
        float Ae[4], Be[4];
#pragma unroll
        for (int r = 0; r < 4; ++r) {
            int oc = ocb + r;
            float gg = bnp1[oc], be = bnp1[128 + oc], m = bnp1[256 + oc], vv = bnp1[384 + oc];
            float inv = gg * rsqrtf(vv + EPSV);
            Ae[r] = inv;
            Be[r] = be - m * inv + dcb[oc] * inv;
        }
#pragma unroll
        for (int nt = 0; nt < 2; ++nt) {
            int pxl = wn * 32 + nt * 16 + n16;
            ushort4v pk;
#pragma unroll
            for (int r = 0; r < 4; ++r) {
                float v = acc[mt][nt][r] * Ae[r] + Be[r];
                v = (v > 0.f) ? v : 0.1f * v;
                pk[r] = f2b(v);
            }
            *(ushort4v*)&ot[pxl][ocb] = pk;
        }
    }
    __syncthreads();

    // ---- fused 1x1 conv: K=128 from LDS tile ----
    floatx4 acc1[4][2];
#pragma unroll
    for (int mt = 0; mt < 4; ++mt)
#pragma unroll
        for (int nt = 0; nt < 2; ++nt)
            acc1[mt][nt] = (floatx4){0.f, 0.f, 0.f, 0.f};

#pragma unroll
    for (int s = 0; s < 4; ++s) {
        short8 a[4], bfr[2];
#pragma unroll
        for (int nt = 0; nt < 2; ++nt)
            bfr[nt] = *(const short8*)&ot[wn * 32 + nt * 16 + n16][s * 32 + quad * 8];
#pragma unroll
        for (int mt = 0; mt < 4; ++mt)
            a[mt] = *(const short8*)&wfC[((size_t)(s * 8 + wm * 4 + mt) * 64 + lane) * 8];
#pragma unroll
        for (int mt = 0; mt < 4; ++mt)
#pragma unroll
            for (int nt = 0; nt < 2; ++nt)
                acc1[mt][nt] = __builtin_amdgcn_mfma_f32_16x16x32_bf16(a[mt], bfr[nt], acc1[mt][nt], 0, 0, 0);
    }

#pragma unroll
    for (int mt = 0; mt < 4; ++mt) {
        const int ocb = (wm * 4 + mt) * 16 + quad * 4;
        float Ae[4], Be[4];
#pragma unroll
        for (int r = 0; r < 4; ++r) {
            int oc = ocb + r;
            float gg = bnp2[oc], be = bnp2[128 + oc], m = bnp2[256 + oc], vv = bnp2[384 + oc];
            float inv = gg * rsqrtf(vv + EPSV);
            Ae[r] = inv;
            Be[r] = be - m * inv;
        }
#pragma unroll
        for (int nt = 0; nt < 2; ++nt) {
            int pxg2 = h * 128 + w0 + wn * 32 + nt * 16 + n16;
            ushort4v rv = *(const ushort4v*)&xres[((size_t)((b << 14) + pxg2)) * 128 + ocb];
#pragma unroll
            for (int r = 0; r < 4; ++r) {
                int oc = ocb + r;
                float v = acc1[mt][nt][r] * Ae[r] + Be[r];
                v = (v > 0.f) ? v : 0.1f * v;
                v += b2f(rv[r]);
                out[(((size_t)b * 128 + oc) << 14) + pxg2] = v;
            }
        }
    }
}

// ---------------------------------------------------------------------------
extern "C" void kernel_launch(void* const* d_in, const int* in_sizes, int n_in,
                              void* d_out, int out_size, void* d_ws, size_t ws_size,
                              hipStream_t stream) {
    const float* x      = (const float*)d_in[0];
    const float* rb_w1  = (const float*)d_in[1];
    const float* rb_b1  = (const float*)d_in[2];
    const float* rb_bn1 = (const float*)d_in[3];
    const float* rb_w2  = (const float*)d_in[4];
    const float* rb_b2  = (const float*)d_in[5];
    const float* rb_bn2 = (const float*)d_in[6];
    const float* off_w  = (const float*)d_in[7];
    const float* off_b  = (const float*)d_in[8];
    const float* dc_w   = (const float*)d_in[9];
    const float* dc_b   = (const float*)d_in[10];
    const float* bn1    = (const float*)d_in[11];
    const float* cv2_w  = (const float*)d_in[12];
    const float* bn2    = (const float*)d_in[13];

    char* base = (char*)d_ws;
    const size_t TSZ = (size_t)4 * 16384 * 128 * 2;       // 16.78 MB bf16 tensor
    unsigned short* xb = (unsigned short*)base;            // stays live (residuals)
    unsigned short* h1 = (unsigned short*)(base + TSZ);    // aliased later as offb
    unsigned short* h2 = (unsigned short*)(base + 2 * TSZ);
    unsigned short* wf1 = (unsigned short*)(base + 3 * TSZ);
    unsigned short* wf2 = wf1 + 1152 * 128;
    unsigned short* wfO = wf2 + 1152 * 128;
    unsigned short* wfD = wfO + 1152 * 64;
    unsigned short* wfC = wfD + 1152 * 128;
    float* offb = (float*)h1;            // NCHW fp32 [B][54][HW], 14.16 MB <= TSZ

    dim3 blk(256, 1, 1);
    dim3 grid(256, BB, 1);
    dim3 grid3(128, BB, 1);

    prep_k<<<3104, 256, 0, stream>>>(x, xb, rb_w1, wf1, rb_w2, wf2,
                                     off_w, wfO, dc_w, wfD, cv2_w, wfC);

    // ResBlock
    conv3x3_mfma<4, 1><<<grid3, blk, 0, stream>>>(xb, wf1, rb_b1, rb_bn1, nullptr, (void*)h1);
    conv3x3_mfma<4, 2><<<grid3, blk, 0, stream>>>(h1, wf2, rb_b2, rb_bn2, xb, (void*)h2);
    // offset conv -> NCHW fp32 (writes over h1, which is dead)
    conv3x3_mfma<2, 0><<<grid3, blk, 0, stream>>>(h2, wfO, off_b, nullptr, nullptr, (void*)offb);
    // fused deformable conv + BN + LeakyReLU + 1x1 conv + BN + LeakyReLU + residual
    deform_fused<<<grid, blk, 0, stream>>>(h2, offb, wfD, dc_b, bn1, wfC, bn2, xb, (float*)d_out);
}